// Round 7
// baseline (2548.650 us; speedup 1.0000x reference)
//
#include <hip/hip_runtime.h>
#include <stdint.h>
#include <stddef.h>

// Persistent 2-layer LSTM, V7: block-specialized pipeline. The h1 and h2
// recurrences run CONCURRENTLY on disjoint CUs, coupled only via the 4-deep
// out1 buffer. Cluster = 8 L1-blocks (64 cols) + 16 L2-blocks (32 cols).
// B=128,T=512,D=128,H=512. 8 clusters; grid 192 x 256 threads.

typedef __attribute__((ext_vector_type(8))) short short8;
typedef __attribute__((ext_vector_type(4))) float f32x4;
typedef unsigned long long u64;

#define DEV static __device__ __forceinline__
#define SCOPE_AGENT __HIP_MEMORY_SCOPE_AGENT

constexpr int TSEQ = 512;
constexpr int DIN  = 128;
constexpr int HDIM = 512;
constexpr int NCL  = 8;    // clusters (bid&7 -> XCD heuristic; perf-only)
constexpr int BB   = 16;   // batch rows per cluster
constexpr int NL1  = 8;    // layer-1 blocks per cluster (64 cols each)
constexpr int NL2  = 16;   // layer-2 blocks per cluster (32 cols each)

DEV unsigned short f2bf(float f) {
  unsigned u = __float_as_uint(f);
  u += 0x7fffu + ((u >> 16) & 1u);   // RNE
  return (unsigned short)(u >> 16);
}
DEV short8 pack8(float4 a, float4 b) {
  short8 r;
  r[0] = (short)f2bf(a.x); r[1] = (short)f2bf(a.y);
  r[2] = (short)f2bf(a.z); r[3] = (short)f2bf(a.w);
  r[4] = (short)f2bf(b.x); r[5] = (short)f2bf(b.y);
  r[6] = (short)f2bf(b.z); r[7] = (short)f2bf(b.w);
  return r;
}
DEV short8 mk8(u64 lo, u64 hi) {
  union { u64 q[2]; short8 v; } u;
  u.q[0] = lo; u.q[1] = hi; return u.v;
}
DEV f32x4 mfma16(short8 a, short8 b, f32x4 c) {
  return __builtin_amdgcn_mfma_f32_16x16x32_bf16(a, b, c, 0, 0, 0);
}
DEV float sigf(float v) { return 1.f / (1.f + __expf(-v)); }
DEV float tanh_(float v) {
  v = fminf(20.f, fmaxf(-20.f, v));
  float e = __expf(2.f * v);
  return (e - 1.f) / (e + 1.f);
}
// poll: lanes 0..nA-1 watch fa[lane]>=tgtA, lanes 16..16+nB-1 watch fb[..]>=tgtB
DEV void poll2(const unsigned* fa, unsigned tgtA, int nA,
               const unsigned* fb, unsigned tgtB, int nB, int lane) {
  const unsigned* fp = nullptr; unsigned tgt = 0u;
  if (lane < nA) { fp = fa + lane; tgt = tgtA; }
  else if (lane >= 16 && lane < 16 + nB) { fp = fb + (lane - 16); tgt = tgtB; }
  while (true) {
    bool ok = true;
    if (fp) ok = (__hip_atomic_load(fp, __ATOMIC_RELAXED, SCOPE_AGENT) >= tgt);
    if (__all((int)ok)) break;
    __builtin_amdgcn_s_sleep(1);
  }
}

__global__ void zero_ws(unsigned* p, int n) {
  int i = blockIdx.x * 256 + threadIdx.x;
  if (i < n)
    __hip_atomic_store(p + i, 0u, __ATOMIC_RELAXED, SCOPE_AGENT);
}

// LDS slab swizzle on short-index: byte ^ ((row&15)<<4)
#define SWZ(row, idx) ((idx) ^ (((row) & 15) << 3))

__global__ __launch_bounds__(256, 1) void lstm_pipe(
    const float* __restrict__ x,
    const float* __restrict__ Wih1, const float* __restrict__ Whh1,
    const float* __restrict__ bih1, const float* __restrict__ bhh1,
    const float* __restrict__ Wih2, const float* __restrict__ Whh2,
    const float* __restrict__ bih2, const float* __restrict__ bhh2,
    float* __restrict__ out,
    unsigned short* __restrict__ buf1,   // [4][NCL][BB][HDIM] bf16 out1/h1
    unsigned short* __restrict__ buf2,   // [2][NCL][BB][HDIM] bf16 h2
    unsigned* __restrict__ flags)        // [NCL][64]: A=0..7, B=16..31
{
  __shared__ union {
    struct { short xs[16 * DIN]; short h1s[16 * HDIM]; float red[4 * 16 * 66]; } l1;
    struct { short o1s[16 * HDIM]; short h2s[16 * HDIM]; float red[8 * 16 * 34]; } l2;
  } sm;

  const int tid  = threadIdx.x;
  const int lane = tid & 63;
  const int lm   = lane & 15;   // A row (batch row) / C col index
  const int lq   = lane >> 4;   // k-octet / C row group
  const int wv   = tid >> 6;    // wave 0..3

  const int bid     = blockIdx.x;
  const int cluster = bid & 7;
  const int idx     = bid >> 3;       // 0..23
  const int cb      = cluster * BB;
  unsigned* flagA = flags + cluster * 64;
  unsigned* flagB = flags + cluster * 64 + 16;

  const int srow = tid >> 4, sseg = tid & 15;   // staging map (16B granules)

  if (idx < NL1) {
    // ================= LAYER-1 BLOCK: 64 cols at j*64 =================
    const int j = idx;
    // wave wv owns gate wv, full K. frags [nt(4)][ks(20)] = 320 VGPR.
    short8 wf[4][20];
    #pragma unroll
    for (int nt = 0; nt < 4; ++nt) {
      const int gr = wv * HDIM + j * 64 + nt * 16 + lm;
      #pragma unroll
      for (int ks = 0; ks < 20; ++ks) {
        const int k0 = ks * 32 + 8 * lq;
        const float* src = (k0 < DIN) ? (Wih1 + (size_t)gr * DIN + k0)
                                      : (Whh1 + (size_t)gr * HDIM + (k0 - DIN));
        wf[nt][ks] = pack8(*(const float4*)src, *(const float4*)(src + 4));
      }
    }
    const int pcol = tid & 63, prg = tid >> 6;   // pickup: col, row-group
    float b1r[4];
    #pragma unroll
    for (int g = 0; g < 4; ++g)
      b1r[g] = bih1[g * HDIM + j * 64 + pcol] + bhh1[g * HDIM + j * 64 + pcol];
    float c1p[4] = {0.f, 0.f, 0.f, 0.f};

    for (int it = 0; it < TSEQ; ++it) {
      // x loads (issue before poll; latency hides under the wait)
      const float* xp = x + ((size_t)(cb + srow) * TSEQ + it) * DIN + sseg * 8;
      const float4 xa = *(const float4*)xp, xb = *(const float4*)(xp + 4);
      // wait: h1_{it-1} published (A>=it) and buf1 slot free (B>=it-3)
      if (it > 0)
        poll2(flagA, (unsigned)it, NL1,
              flagB, (it >= 3) ? (unsigned)(it - 3) : 0u, NL2, lane);
      // stage x_t
      *(short8*)(&sm.l1.xs[SWZ(srow, srow * DIN + sseg * 8)]) = pack8(xa, xb);
      // stage h1_{it-1} from slot (it-1)&3
      {
        const unsigned short* h1r =
            buf1 + (size_t)((((it + 3) & 3) * NCL + cluster) * BB) * HDIM;
        const u64* s = (const u64*)(h1r + (size_t)srow * HDIM + sseg * 32);
        u64 q[8];
        #pragma unroll
        for (int q8 = 0; q8 < 8; ++q8)
          q[q8] = __hip_atomic_load(s + q8, __ATOMIC_RELAXED, SCOPE_AGENT);
        #pragma unroll
        for (int c = 0; c < 4; ++c)
          *(short8*)(&sm.l1.h1s[SWZ(srow, srow * HDIM + sseg * 32 + c * 8)]) =
              mk8(q[2 * c], q[2 * c + 1]);
      }
      __syncthreads();
      // MFMA: 20 K-steps x 4 N-tiles, gate = wv
      f32x4 z = {0.f, 0.f, 0.f, 0.f};
      f32x4 acc[4] = {z, z, z, z};
      #pragma unroll
      for (int ks = 0; ks < 20; ++ks) {
        short8 a;
        if (ks < 4)
          a = *(const short8*)(&sm.l1.xs[SWZ(lm, lm * DIN + ks * 32 + 8 * lq)]);
        else
          a = *(const short8*)(&sm.l1.h1s[SWZ(lm, lm * HDIM + (ks - 4) * 32 + 8 * lq)]);
        #pragma unroll
        for (int nt = 0; nt < 4; ++nt) acc[nt] = mfma16(a, wf[nt][ks], acc[nt]);
      }
      #pragma unroll
      for (int nt = 0; nt < 4; ++nt)
        #pragma unroll
        for (int r = 0; r < 4; ++r)
          sm.l1.red[wv * 1056 + (lq * 4 + r) * 66 + nt * 16 + lm] = acc[nt][r];
      __syncthreads();
      // pickup: 4 (row,col) pairs per thread; publish h1_t to slot it&3
      unsigned short* wp =
          buf1 + (size_t)(((it & 3) * NCL + cluster) * BB) * HDIM;
      #pragma unroll
      for (int p = 0; p < 4; ++p) {
        const int row = prg * 4 + p;
        float pg[4];
        #pragma unroll
        for (int g = 0; g < 4; ++g)
          pg[g] = b1r[g] + sm.l1.red[g * 1056 + row * 66 + pcol];
        const float i_ = sigf(pg[0]), f_ = sigf(pg[1]);
        const float g_ = tanh_(pg[2]), o_ = sigf(pg[3]);
        c1p[p] = f_ * c1p[p] + i_ * g_;
        const float h1v = o_ * tanh_(c1p[p]);
        __hip_atomic_store(&wp[(size_t)row * HDIM + j * 64 + pcol], f2bf(h1v),
                           __ATOMIC_RELAXED, SCOPE_AGENT);
      }
      __syncthreads();   // drains vmcnt: all publishes complete
      if (tid == 0)
        __hip_atomic_store(flagA + j, (unsigned)(it + 1),
                           __ATOMIC_RELAXED, SCOPE_AGENT);
    }
  } else {
    // ================= LAYER-2 BLOCK: 32 cols at j2*32 =================
    const int j2 = idx - NL1;            // 0..15
    const int kh = wv >> 1, gp = wv & 1; // K-half, gate-pair
    // frags [gg(2)][nt(2)][ks(16)] = 256 VGPR
    short8 wf[2][2][16];
    #pragma unroll
    for (int gg = 0; gg < 2; ++gg) {
      #pragma unroll
      for (int nt = 0; nt < 2; ++nt) {
        const int g  = 2 * gp + gg;
        const int gr = g * HDIM + j2 * 32 + nt * 16 + lm;
        #pragma unroll
        for (int ks = 0; ks < 16; ++ks) {
          const int k0 = (kh * 16 + ks) * 32 + 8 * lq;   // 0..1023
          const float* src = (k0 < HDIM) ? (Wih2 + (size_t)gr * HDIM + k0)
                                         : (Whh2 + (size_t)gr * HDIM + (k0 - HDIM));
          wf[gg][nt][ks] = pack8(*(const float4*)src, *(const float4*)(src + 4));
        }
      }
    }
    const int pcol = tid & 31, pr8 = tid >> 5;   // pickup: col, row-group
    float b2r[4];
    #pragma unroll
    for (int g = 0; g < 4; ++g)
      b2r[g] = bih2[g * HDIM + j2 * 32 + pcol] + bhh2[g * HDIM + j2 * 32 + pcol];
    float c2p[2] = {0.f, 0.f};

    for (int t2 = 0; t2 < TSEQ; ++t2) {
      // wait: out1_{t2} available (A>=t2+1), peers' h2_{t2-1} published (B>=t2)
      poll2(flagA, (unsigned)(t2 + 1), NL1, flagB, (unsigned)t2, NL2, lane);
      // stage out1_{t2} (slot t2&3) and h2_{t2-1} (slot (t2-1)&1)
      {
        const unsigned short* o1r =
            buf1 + (size_t)(((t2 & 3) * NCL + cluster) * BB) * HDIM;
        const unsigned short* h2r =
            buf2 + (size_t)((((t2 + 1) & 1) * NCL + cluster) * BB) * HDIM;
        const u64* s1 = (const u64*)(o1r + (size_t)srow * HDIM + sseg * 32);
        const u64* s2 = (const u64*)(h2r + (size_t)srow * HDIM + sseg * 32);
        u64 q[8], r8[8];
        #pragma unroll
        for (int q8 = 0; q8 < 8; ++q8) {
          q[q8]  = __hip_atomic_load(s1 + q8, __ATOMIC_RELAXED, SCOPE_AGENT);
          r8[q8] = __hip_atomic_load(s2 + q8, __ATOMIC_RELAXED, SCOPE_AGENT);
        }
        #pragma unroll
        for (int c = 0; c < 4; ++c) {
          *(short8*)(&sm.l2.o1s[SWZ(srow, srow * HDIM + sseg * 32 + c * 8)]) =
              mk8(q[2 * c], q[2 * c + 1]);
          *(short8*)(&sm.l2.h2s[SWZ(srow, srow * HDIM + sseg * 32 + c * 8)]) =
              mk8(r8[2 * c], r8[2 * c + 1]);
        }
      }
      __syncthreads();
      // MFMA: K-half kh, gates 2gp..2gp+1, 2 N-tiles
      f32x4 z = {0.f, 0.f, 0.f, 0.f};
      f32x4 acc[2][2] = {{z, z}, {z, z}};
      const short* slab = kh ? sm.l2.h2s : sm.l2.o1s;
      #pragma unroll
      for (int ks = 0; ks < 16; ++ks) {
        const short8 a =
            *(const short8*)(&slab[SWZ(lm, lm * HDIM + ks * 32 + 8 * lq)]);
        #pragma unroll
        for (int gg = 0; gg < 2; ++gg)
          #pragma unroll
          for (int nt = 0; nt < 2; ++nt)
            acc[gg][nt] = mfma16(a, wf[gg][nt][ks], acc[gg][nt]);
      }
      #pragma unroll
      for (int gg = 0; gg < 2; ++gg) {
        const int g = 2 * gp + gg;
        #pragma unroll
        for (int nt = 0; nt < 2; ++nt)
          #pragma unroll
          for (int r = 0; r < 4; ++r)
            sm.l2.red[((kh * 4 + g) * 16 + lq * 4 + r) * 34 + nt * 16 + lm] =
                acc[gg][nt][r];
      }
      __syncthreads();
      // pickup: 2 (row,col) pairs; publish h2 or final out
      #pragma unroll
      for (int p = 0; p < 2; ++p) {
        const int row = pr8 * 2 + p;
        float pg[4];
        #pragma unroll
        for (int g = 0; g < 4; ++g)
          pg[g] = b2r[g] + sm.l2.red[(g * 16 + row) * 34 + pcol]
                         + sm.l2.red[((4 + g) * 16 + row) * 34 + pcol];
        const float i_ = sigf(pg[0]), f_ = sigf(pg[1]);
        const float g_ = tanh_(pg[2]), o_ = sigf(pg[3]);
        c2p[p] = f_ * c2p[p] + i_ * g_;
        const float h2v = o_ * tanh_(c2p[p]);
        if (t2 < TSEQ - 1) {
          unsigned short* wp =
              buf2 + (size_t)(((t2 & 1) * NCL + cluster) * BB) * HDIM;
          __hip_atomic_store(&wp[(size_t)row * HDIM + j2 * 32 + pcol], f2bf(h2v),
                             __ATOMIC_RELAXED, SCOPE_AGENT);
        } else {
          const int b = cb + row;
          out[(size_t)b * HDIM + j2 * 32 + pcol] = h2v;
          out[(size_t)128 * HDIM + (size_t)b * HDIM + j2 * 32 + pcol] = c2p[p];
        }
      }
      __syncthreads();   // drains vmcnt: all publishes complete
      if (tid == 0 && t2 < TSEQ - 1)
        __hip_atomic_store(flagB + j2, (unsigned)(t2 + 1),
                           __ATOMIC_RELAXED, SCOPE_AGENT);
    }
  }
}

extern "C" void kernel_launch(void* const* d_in, const int* in_sizes, int n_in,
                              void* d_out, int out_size, void* d_ws, size_t ws_size,
                              hipStream_t stream) {
  const float* x    = (const float*)d_in[0];
  const float* Wih1 = (const float*)d_in[1];
  const float* Whh1 = (const float*)d_in[2];
  const float* bih1 = (const float*)d_in[3];
  const float* bhh1 = (const float*)d_in[4];
  const float* Wih2 = (const float*)d_in[5];
  const float* Whh2 = (const float*)d_in[6];
  const float* bih2 = (const float*)d_in[7];
  const float* bhh2 = (const float*)d_in[8];
  float* out = (float*)d_out;

  const size_t buf1Elems = (size_t)4 * NCL * BB * HDIM;   // 262144 ushorts
  const size_t buf2Elems = (size_t)2 * NCL * BB * HDIM;   // 131072 ushorts
  unsigned short* buf1 = (unsigned short*)d_ws;
  unsigned short* buf2 = buf1 + buf1Elems;
  unsigned* flags = (unsigned*)(buf2 + buf2Elems);

  const int nzero = (int)(((buf1Elems + buf2Elems) * 2 + NCL * 64 * 4) / 4);
  zero_ws<<<(nzero + 255) / 256, 256, 0, stream>>>((unsigned*)d_ws, nzero);
  lstm_pipe<<<(NL1 + NL2) * NCL, 256, 0, stream>>>(
      x, Wih1, Whh1, bih1, bhh1, Wih2, Whh2, bih2, bhh2,
      out, buf1, buf2, flags);
}